// Round 9
// baseline (158.999 us; speedup 1.0000x reference)
//
#include <hip/hip_runtime.h>
#include <math.h>

// ---------------------------------------------------------------------------
// GaussianQuant — MFMA-filtered argmax, R21 (DIAGNOSTIC: R19 + merge x2).
// R18/R19/R20 all nulled within 1us -> the cost model for the ~103us
// non-filter residue is wrong. Top-5 visibility is cut at the 42us fills, so
// merge/prep durations are invisible. This round measures T_merge by
// difference: merge is IDEMPOTENT (reads only prep/filter outputs; writes
// deterministic values; no atomics), so launching it twice is bit-identical
// and dur_us - 133.7 == T_merge.
//   branch A: dur ~160-175 -> merge 30-42us -> next: packed-index filter
//             (R13 trick) to make merge ~5us.
//   branch B: dur ~140-145 -> merge 8-12us -> hole is fixed overhead ->
//             next: fuse prep; then near practical limit.
// Kernel code below is R19 VERBATIM (best total, 133.7us).
// ---------------------------------------------------------------------------

typedef _Float16 half8 __attribute__((ext_vector_type(8)));
typedef float f32x4 __attribute__((ext_vector_type(4)));

#define DIM 32
#define NROWS 16384
#define KSIZE 16384
#define NSPLIT 16
#define SPLITK 1024
#define NCOL 256

// ws layout (bytes); [0,4096) zeroed by memset each launch
#define WS_M1   0                       // 32 float (atomicMax targets)
#define WS_KL   256                     // 1 double (atomicAdd target)
#define WS_CN1  512                     // 256 float (atomicMax: max ||c_k||)
#define WS_CN2  1536                    // 256 float (atomicMax: max ||c_k^2||)
#define WS_PQ   4096                    // 4 MB fp32 [row][64]
#define WS_AH   (WS_PQ + 4194304)       // 2 MB fp16 [row][64]
#define WS_BH   (WS_AH + 2097152)       // 2 MB fp16 [k][64] PRE-SWIZZLED
#define WS_W1   (WS_BH + 2097152)       // 8 MB fp16 [split][row][16]

// Fused prep, 1024 blocks: [0,512) pack codebook (swizzled) + per-dim max +
// per-column norm maxima; [512,1024) compute p,q + fp16 pack + KL partial.
__global__ __launch_bounds__(256) void prep_kernel(const float* __restrict__ cb,
                                                   const float* __restrict__ z,
                                                   _Float16* __restrict__ Bh,
                                                   float* __restrict__ M1,
                                                   float* __restrict__ CN1,
                                                   float* __restrict__ CN2,
                                                   float* __restrict__ PQ,
                                                   _Float16* __restrict__ Ah,
                                                   double* __restrict__ klsum) {
  const int w = threadIdx.x >> 6, l = threadIdx.x & 63;
  const int sub = l >> 5, d = l & 31;
  if (blockIdx.x < 512) {
    __shared__ float lm[8][DIM];
    float m = 0.0f;
#pragma unroll
    for (int i = 0; i < 4; ++i) {
      const int k = blockIdx.x * 32 + i * 8 + w * 2 + sub;
      const float c = cb[k * DIM + d];
      // swizzled slot layout: logical slot s (8 halfs) stored at s ^ (k&7)
      const int key = k & 7;
      const int sc = (d >> 3) ^ key;          // c-part: logical slot d>>3
      const int sq = (4 + (d >> 3)) ^ key;    // c^2-part: logical slot 4+d>>3
      Bh[(size_t)k * 64 + sc * 8 + (d & 7)] = (_Float16)c;
      Bh[(size_t)k * 64 + sq * 8 + (d & 7)] = (_Float16)(c * c);
      m = fmaxf(m, fabsf(c));
      // per-k norms -> per-column maxima (col = (k>>10)*16 + (k&15))
      float s2 = c * c, s4 = c * c * c * c;
#pragma unroll
      for (int mask = 1; mask <= 16; mask <<= 1) {
        s2 += __shfl_xor(s2, mask);
        s4 += __shfl_xor(s4, mask);
      }
      if (d == 0) {
        const int col = (k >> 10) * 16 + (k & 15);
        atomicMax((unsigned*)&CN1[col], __float_as_uint(sqrtf(s2)));
        atomicMax((unsigned*)&CN2[col], __float_as_uint(sqrtf(s4)));
      }
    }
    lm[threadIdx.x >> 5][d] = m;
    __syncthreads();
    if (threadIdx.x < DIM) {
      float x = lm[0][threadIdx.x];
#pragma unroll
      for (int i = 1; i < 8; ++i) x = fmaxf(x, lm[i][threadIdx.x]);
      atomicMax((unsigned*)&M1[threadIdx.x], __float_as_uint(x));
    }
  } else {
    const int blk = blockIdx.x - 512;
    double kacc = 0.0;
#pragma unroll 1
    for (int i = 0; i < 4; ++i) {
      const int row = blk * 32 + i * 8 + w * 2 + sub;
      const int t = row >> 3, c = row & 7;
      const float mu = z[t * 512 + d * 8 + c];
      float lv = z[t * 512 + 256 + d * 8 + c];
      lv = fminf(fmaxf(lv, -30.0f), 20.0f);
      const float stdv = expf(0.5f * lv);
      const float iv = 1.0f / (stdv * stdv);   // identical to R2 expression
      const float p = mu * iv;
      const float q = 0.5f * (1.0f - iv);
      PQ[(size_t)row * 64 + d] = p;
      PQ[(size_t)row * 64 + 32 + d] = q;
      Ah[(size_t)row * 64 + d] = (_Float16)p;
      Ah[(size_t)row * 64 + 32 + d] = (_Float16)q;
      kacc += (double)(mu * mu + stdv * stdv - 1.0f - lv);
    }
#pragma unroll
    for (int off = 32; off > 0; off >>= 1) kacc += __shfl_down(kacc, off);
    __shared__ double wsum[4];
    if (l == 0) wsum[w] = kacc;
    __syncthreads();
    if (threadIdx.x == 0)
      atomicAdd(klsum, (wsum[0] + wsum[1]) + (wsum[2] + wsum[3]));
  }
}

// async global->LDS, 16B per lane; dest must be linear in lane order.
__device__ __forceinline__ void gload_lds16(const _Float16* g, _Float16* l) {
  __builtin_amdgcn_global_load_lds(
      (__attribute__((address_space(1))) void*)(g),
      (__attribute__((address_space(3))) void*)(l), 16, 0, 0);
}

// grid (32, 16): x = rowgroup (512 rows), y = split. 4 waves x 128 rows each
// (8 rowtiles, A resident = 64 VGPR). B staged through 2 x 32 KB LDS buffers
// (16 tiles/chunk) via global_load_lds; 4 chunks, 1 barrier each.
__global__ __launch_bounds__(256, 2) void filter_kernel(const _Float16* __restrict__ Ah,
                                                        const _Float16* __restrict__ Bh,
                                                        _Float16* __restrict__ W1) {
  __shared__ _Float16 sB[2][16384];   // 2 x 32 KB
  const int tid = threadIdx.x;
  const int lane = tid & 63;
  const int wave = tid >> 6;
  const int split = blockIdx.y;
  const int rowbase = blockIdx.x * 512 + wave * 128;   // 8 rowtiles of 16
  const int c16 = lane & 15, quad = lane >> 4;

  const _Float16* gB = Bh + (size_t)split * SPLITK * 64;  // 128 KB region

  // async-stage chunk 0 -> buf 0 (linear copy: Bh pre-swizzled in prep)
#pragma unroll
  for (int j = 0; j < 8; ++j)
    gload_lds16(gB + j * 2048 + tid * 8, &sB[0][j * 2048 + tid * 8]);

  half8 uh0[8], uh1[8];
#pragma unroll
  for (int rt = 0; rt < 8; ++rt) {
    const size_t abase = (size_t)(rowbase + rt * 16 + c16) * 64 + quad * 8;
    uh0[rt] = *(const half8*)(Ah + abase);
    uh1[rt] = *(const half8*)(Ah + abase + 32);
  }

  float a1[8][4];
#pragma unroll
  for (int rt = 0; rt < 8; ++rt)
#pragma unroll
    for (int r = 0; r < 4; ++r) a1[rt][r] = -INFINITY;

  const f32x4 fzero = {0.f, 0.f, 0.f, 0.f};
  // swizzled read offsets (halfs): row c16, physical slot = logical ^ (c16&7)
  const int key = c16 & 7;
  const int rs0h = c16 * 64 + (quad ^ key) * 8;         // p-part (slots 0-3)
  const int rs1h = c16 * 64 + ((quad + 4) ^ key) * 8;   // q-part (slots 4-7)

  __syncthreads();   // chunk 0 landed (compiler drains vmcnt before barrier)

#pragma unroll 1
  for (int ch = 0; ch < 4; ++ch) {
    if (ch < 3) {    // issue next chunk into the idle buffer (async)
      const _Float16* src = gB + (size_t)(ch + 1) * 16384;
      _Float16* dst = &sB[(ch + 1) & 1][0];
#pragma unroll
      for (int j = 0; j < 8; ++j)
        gload_lds16(src + j * 2048 + tid * 8, dst + j * 2048 + tid * 8);
    }
    const _Float16* buf = &sB[ch & 1][0];
#pragma unroll 1
    for (int tp = 0; tp < 8; ++tp) {          // 8 tile-pairs per chunk
      const _Float16* b0 = buf + (2 * tp) * 1024;
      const _Float16* b1 = b0 + 1024;
      const half8 x0 = *(const half8*)(b0 + rs0h);
      const half8 x1 = *(const half8*)(b0 + rs1h);
      const half8 y0 = *(const half8*)(b1 + rs0h);
      const half8 y1 = *(const half8*)(b1 + rs1h);
#pragma unroll
      for (int rt = 0; rt < 8; ++rt) {
        f32x4 h0 = __builtin_amdgcn_mfma_f32_16x16x32_f16(uh0[rt], x0, fzero, 0, 0, 0);
        h0 = __builtin_amdgcn_mfma_f32_16x16x32_f16(uh1[rt], x1, h0, 0, 0, 0);
        f32x4 h1 = __builtin_amdgcn_mfma_f32_16x16x32_f16(uh0[rt], y0, fzero, 0, 0, 0);
        h1 = __builtin_amdgcn_mfma_f32_16x16x32_f16(uh1[rt], y1, h1, 0, 0, 0);
#pragma unroll
        for (int r = 0; r < 4; ++r)
          a1[rt][r] = fmaxf(fmaxf(h0[r], h1[r]), a1[rt][r]);   // v_max3
      }
    }
    __syncthreads();  // all waves done with buf; next chunk landed (vmcnt 0)
  }

  // W1 fp16 [split][row][16]: block-exclusive contiguous 16KB, no RMW.
  // Low-clamp kills -inf (sound over-estimate); high-side rounding covered
  // by merge's 5e-4*|w| bound term.
#pragma unroll
  for (int rt = 0; rt < 8; ++rt)
#pragma unroll
    for (int r = 0; r < 4; ++r) {
      const int row_r = rowbase + rt * 16 + quad * 4 + r;   // C: row=quad*4+r
      W1[((size_t)split * NROWS + row_r) * 16 + c16] =
          (_Float16)fmaxf(a1[rt][r], -65504.0f);
    }
}

// exact fp32 score, p/q broadcast from LDS (identical formula to R2)
__device__ __forceinline__ float exact_score(const float4* __restrict__ cb4,
                                             const float4* __restrict__ spq,
                                             int k) {
  float s0 = 0.0f, s1 = 0.0f, s2 = 0.0f, s3 = 0.0f;
#pragma unroll
  for (int m = 0; m < 8; ++m) {
    const float4 cv = cb4[k * 8 + m];
    const float4 pv = spq[m];        // p[4m..4m+3]
    const float4 qv = spq[8 + m];    // q[4m..4m+3]
    s0 = fmaf(cv.x, fmaf(qv.x, cv.x, pv.x), s0);
    s1 = fmaf(cv.y, fmaf(qv.y, cv.y, pv.y), s1);
    s2 = fmaf(cv.z, fmaf(qv.z, cv.z, pv.z), s2);
    s3 = fmaf(cv.w, fmaf(qv.w, cv.w, pv.w), s3);
  }
  return (s0 + s1) + (s2 + s3);
}

// 1 wave per row; 4 rows per block. Seed E* by fully rescanning the argmax
// column, then full rescan of every column with w + Btot_col >= E*.
// Btot_col = C-S bound + slack + 5e-4*|w| (fp16 W1 rounding).
__global__ __launch_bounds__(256, 4) void merge_kernel(const float* __restrict__ PQ,
                                                       const float* __restrict__ cb,
                                                       const _Float16* __restrict__ W1,
                                                       const float* __restrict__ CN1,
                                                       const float* __restrict__ CN2,
                                                       const double* __restrict__ klsum,
                                                       float* __restrict__ out0,
                                                       float* __restrict__ out1,
                                                       float* __restrict__ out2) {
  __shared__ float4 spq_s[4][16];
  const int lane = threadIdx.x & 63;
  const int wave = threadIdx.x >> 6;
  const int row = blockIdx.x * 4 + wave;

  if (lane < 16)
    spq_s[wave][lane] = ((const float4*)(PQ + (size_t)row * 64))[lane];
  __syncthreads();
  const float4* spq = spq_s[wave];
  const float4* __restrict__ cb4 = (const float4*)cb;

  // per-row norms ||p||2, ||q||2
  float sp = 0.0f, sq = 0.0f;
  if (lane < DIM) {
    const float pd = ((const float*)spq)[lane];
    const float qd = ((const float*)spq)[32 + lane];
    sp = pd * pd;
    sq = qd * qd;
  }
#pragma unroll
  for (int off = 1; off < 32; off <<= 1) {
    sp += __shfl_xor(sp, off);
    sq += __shfl_xor(sq, off);
  }
  const float pn = sqrtf(__shfl(sp, 0));
  const float qn = sqrtf(__shfl(sq, 0));

  // load 256 column maxima (fp16, layout [split][row][16]); col = i*64 + lane
  float w[4];
#pragma unroll
  for (int i = 0; i < 4; ++i)
    w[i] = (float)W1[((size_t)(i * 4 + (lane >> 4)) * NROWS + row) * 16 + (lane & 15)];
  float As = fmaxf(fmaxf(w[0], w[1]), fmaxf(w[2], w[3]));
#pragma unroll
  for (int off = 1; off < 64; off <<= 1) As = fmaxf(As, __shfl_xor(As, off));
  const float slack = 2e-5f * (fabsf(As) + 1.0f) + 1e-3f;

  // per-column rigorous bounds + fp16-rounding term
  float bt[4];
#pragma unroll
  for (int i = 0; i < 4; ++i) {
    const int col = i * 64 + lane;
    bt[i] = 1.05e-3f * (pn * CN1[col] + qn * CN2[col]) + slack
            + 5e-4f * fabsf(w[i]);
  }

  // ---- seed: full exact rescan of (one) column achieving As ----
  int done_col = -1;
#pragma unroll
  for (int i = 0; i < 4; ++i) {
    if (done_col < 0) {
      const unsigned long long m = __ballot(w[i] == As);
      if (m) done_col = i * 64 + __builtin_ctzll(m);
    }
  }
  const int k0 = (done_col >> 4) * SPLITK + lane * 16 + (done_col & 15);
  float best = exact_score(cb4, spq, k0);
  int bk = k0;
#pragma unroll
  for (int off = 1; off < 64; off <<= 1) {
    const float ov = __shfl_xor(best, off);
    const int ok = __shfl_xor(bk, off);
    if (ov > best || (ov == best && ok < bk)) { best = ov; bk = ok; }
  }
  const float Estar = best;   // exact score of a real k; all lanes agree

  // ---- full rescan of every other column that could still hold the max ----
#pragma unroll 1
  for (int i = 0; i < 4; ++i) {
    unsigned long long m = __ballot(w[i] + bt[i] >= Estar);
    if ((done_col >> 6) == i) m &= ~(1ull << (done_col & 63));
    while (m) {
      const int e = __builtin_ctzll(m);
      m &= m - 1;
      const int col = i * 64 + e;
      const int k = (col >> 4) * SPLITK + lane * 16 + (col & 15);
      const float sc = exact_score(cb4, spq, k);
      if (sc > best || (sc == best && k < bk)) { best = sc; bk = k; }
    }
  }
  // final cross-lane argmax, min-k on ties (numpy first-max)
#pragma unroll
  for (int off = 1; off < 64; off <<= 1) {
    const float ov = __shfl_xor(best, off);
    const int ok = __shfl_xor(bk, off);
    if (ov > best || (ov == best && ok < bk)) { best = ov; bk = ok; }
  }
  if (lane == 0) out2[row] = (float)bk;
  const int tt = row >> 3, cc = row & 7;
  if (lane < DIM) out0[tt * 256 + lane * 8 + cc] = cb[bk * DIM + lane];
  if (blockIdx.x == 0 && threadIdx.x == 0)
    out1[0] = (float)(klsum[0] * (1.4426 * 0.5) / (double)NROWS);
}

extern "C" void kernel_launch(void* const* d_in, const int* in_sizes, int n_in,
                              void* d_out, int out_size, void* d_ws, size_t ws_size,
                              hipStream_t stream) {
  const float* z  = (const float*)d_in[0];
  const float* cb = (const float*)d_in[2];   // d_in[1]=noise unused (STE cancels)

  char* ws = (char*)d_ws;
  float*      M1 = (float*)(ws + WS_M1);
  double* klsum  = (double*)(ws + WS_KL);
  float*     CN1 = (float*)(ws + WS_CN1);
  float*     CN2 = (float*)(ws + WS_CN2);
  float*      PQ = (float*)(ws + WS_PQ);
  _Float16*   Ah = (_Float16*)(ws + WS_AH);
  _Float16*   Bh = (_Float16*)(ws + WS_BH);
  _Float16*   W1 = (_Float16*)(ws + WS_W1);

  float* out0 = (float*)d_out;            // 524288
  float* out1 = out0 + 524288;            // 1
  float* out2 = out1 + 1;                 // 16384

  (void)hipMemsetAsync(ws, 0, 4096, stream);   // M1, klsum, CN1, CN2 = 0
  prep_kernel<<<1024, 256, 0, stream>>>(cb, z, Bh, M1, CN1, CN2, PQ, Ah, klsum);
  dim3 fgrid(32, NSPLIT);
  filter_kernel<<<fgrid, 256, 0, stream>>>(Ah, Bh, W1);
  // DIAGNOSTIC: merge launched TWICE (idempotent). dur_us - 133.7 = T_merge.
  merge_kernel<<<NROWS / 4, 256, 0, stream>>>(PQ, cb, W1, CN1, CN2, klsum,
                                              out0, out1, out2);
  merge_kernel<<<NROWS / 4, 256, 0, stream>>>(PQ, cb, W1, CN1, CN2, klsum,
                                              out0, out1, out2);
}

// Round 10
// 128.445 us; speedup vs baseline: 1.2379x; 1.2379x over previous
//
#include <hip/hip_runtime.h>
#include <math.h>

// ---------------------------------------------------------------------------
// GaussianQuant — MFMA-filtered argmax, R22.
// score[n,k] = sum_d p*c + q*c^2;  u=[p,q], v=[c,c^2], score = u.v  (K=64)
// fp16 HI-ONLY approx, rigorous per-k error:
//   err_k <= 1.05e-3 * (||p||2*||c_k||2 + ||q||2*||c_k^2||2)   (Cauchy-Schwarz)
// R21 diagnostic: T_merge = 25.3us (measured by idempotent double-launch).
// Budget: 133.7 = fill ~43 + merge 25.3 + filter ~22-30 + PREP+gaps ~30-40.
// R22 rewrites prep (carried verbatim since R13, never optimized):
//   - z-half: wave=token; float4 mu/lv loads COALESCED (j=4*lane+e maps to
//     d=lane>>1, c=(lane&1)*4+e); PQ/Ah stores land as contiguous 128B/64B
//     segments per store-instruction (even lanes d=0..31, odd lanes 2nd seg).
//   - cb-half: lane owns one PHYSICAL 8-half slot of one k; logical =
//     s_phys^(k&7); one 16-B half8 store (wave = 1KB contiguous) replaces
//     16 scattered 2-B stores. Norms: 6 shuffles (8-lane groups) vs 40.
//   - M1 DELETED (dead since R18: merge uses CN1/CN2 only).
// Bh/Ah/PQ values bit-identical (same float exprs); CN/KL reorder absorbed
// by slack/double. filter+merge = R19 VERBATIM (single merge).
// ---------------------------------------------------------------------------

typedef _Float16 half8 __attribute__((ext_vector_type(8)));
typedef float f32x4 __attribute__((ext_vector_type(4)));

#define DIM 32
#define NROWS 16384
#define KSIZE 16384
#define NSPLIT 16
#define SPLITK 1024
#define NCOL 256

// ws layout (bytes); [0,4096) zeroed by memset each launch
#define WS_M1   0                       // (unused, kept for layout stability)
#define WS_KL   256                     // 1 double (atomicAdd target)
#define WS_CN1  512                     // 256 float (atomicMax: max ||c_k||)
#define WS_CN2  1536                    // 256 float (atomicMax: max ||c_k^2||)
#define WS_PQ   4096                    // 4 MB fp32 [row][64]
#define WS_AH   (WS_PQ + 4194304)       // 2 MB fp16 [row][64]
#define WS_BH   (WS_AH + 2097152)       // 2 MB fp16 [k][64] PRE-SWIZZLED
#define WS_W1   (WS_BH + 2097152)       // 8 MB fp16 [split][row][16]

// Fused prep, 1024 blocks:
// [0,512): codebook pack (swizzled, 16-B stores) + per-column norm maxima.
//          Each wave: 8 k's; lane = (k_local<<3) | s_phys.
// [512,1024): p,q + fp16 pack + KL partial. Each wave: 1 token, coalesced.
__global__ __launch_bounds__(256) void prep_kernel(const float* __restrict__ cb,
                                                   const float* __restrict__ z,
                                                   _Float16* __restrict__ Bh,
                                                   float* __restrict__ CN1,
                                                   float* __restrict__ CN2,
                                                   float* __restrict__ PQ,
                                                   _Float16* __restrict__ Ah,
                                                   double* __restrict__ klsum) {
  const int w = threadIdx.x >> 6, l = threadIdx.x & 63;
  if (blockIdx.x < 512) {
    // ---- codebook half: 32 k's per block (8 per wave) ----
    const int k = blockIdx.x * 32 + w * 8 + (l >> 3);
    const int s_phys = l & 7;
    const int logical = s_phys ^ (k & 7);
    const int base = (logical & 3) * 8;            // dim group start
    const float4 cA = *(const float4*)(cb + k * DIM + base);
    const float4 cB = *(const float4*)(cb + k * DIM + base + 4);
    float v[8] = {cA.x, cA.y, cA.z, cA.w, cB.x, cB.y, cB.z, cB.w};

    half8 hv;
    if (logical < 4) {
#pragma unroll
      for (int i = 0; i < 8; ++i) hv[i] = (_Float16)v[i];
    } else {
#pragma unroll
      for (int i = 0; i < 8; ++i) hv[i] = (_Float16)(v[i] * v[i]);
    }
    *(half8*)(Bh + (size_t)k * 64 + s_phys * 8) = hv;   // 16-B store, coalesced

    // per-k norms: lanes with logical<4 cover dims 0..31 exactly once
    float s2 = 0.0f, s4 = 0.0f;
    if (logical < 4) {
#pragma unroll
      for (int i = 0; i < 8; ++i) {
        const float c2 = v[i] * v[i];
        s2 += c2;
        s4 += c2 * c2;
      }
    }
#pragma unroll
    for (int mask = 1; mask <= 4; mask <<= 1) {     // 8-lane group reduce
      s2 += __shfl_xor(s2, mask);
      s4 += __shfl_xor(s4, mask);
    }
    if (s_phys == 0) {
      const int col = (k >> 10) * 16 + (k & 15);
      atomicMax((unsigned*)&CN1[col], __float_as_uint(sqrtf(s2)));
      atomicMax((unsigned*)&CN2[col], __float_as_uint(sqrtf(s4)));
    }
  } else {
    // ---- z half: 4 tokens per block (1 per wave), fully coalesced ----
    const int tok = (blockIdx.x - 512) * 4 + w;
    const float4 mu4 = ((const float4*)z)[(size_t)tok * 128 + l];        // mu
    const float4 lv4 = ((const float4*)z)[(size_t)tok * 128 + 64 + l];   // logvar
    const int d = l >> 1;
    const int c0 = (l & 1) * 4;
    double kacc = 0.0;
#pragma unroll
    for (int e = 0; e < 4; ++e) {
      const float mu = ((const float*)&mu4)[e];
      float lv = ((const float*)&lv4)[e];
      lv = fminf(fmaxf(lv, -30.0f), 20.0f);
      const float stdv = expf(0.5f * lv);
      const float iv = 1.0f / (stdv * stdv);   // identical to R2 expression
      const float p = mu * iv;
      const float q = 0.5f * (1.0f - iv);
      const size_t row = (size_t)tok * 8 + c0 + e;
      PQ[row * 64 + d] = p;                    // contiguous across lanes
      PQ[row * 64 + 32 + d] = q;
      Ah[row * 64 + d] = (_Float16)p;
      Ah[row * 64 + 32 + d] = (_Float16)q;
      kacc += (double)(mu * mu + stdv * stdv - 1.0f - lv);
    }
#pragma unroll
    for (int off = 32; off > 0; off >>= 1) kacc += __shfl_down(kacc, off);
    __shared__ double wsum[4];
    if (l == 0) wsum[w] = kacc;
    __syncthreads();
    if (threadIdx.x == 0)
      atomicAdd(klsum, (wsum[0] + wsum[1]) + (wsum[2] + wsum[3]));
  }
}

// async global->LDS, 16B per lane; dest must be linear in lane order.
__device__ __forceinline__ void gload_lds16(const _Float16* g, _Float16* l) {
  __builtin_amdgcn_global_load_lds(
      (__attribute__((address_space(1))) void*)(g),
      (__attribute__((address_space(3))) void*)(l), 16, 0, 0);
}

// grid (32, 16): x = rowgroup (512 rows), y = split. 4 waves x 128 rows each
// (8 rowtiles, A resident = 64 VGPR). B staged through 2 x 32 KB LDS buffers
// (16 tiles/chunk) via global_load_lds; 4 chunks, 1 barrier each. (R19)
__global__ __launch_bounds__(256, 2) void filter_kernel(const _Float16* __restrict__ Ah,
                                                        const _Float16* __restrict__ Bh,
                                                        _Float16* __restrict__ W1) {
  __shared__ _Float16 sB[2][16384];   // 2 x 32 KB
  const int tid = threadIdx.x;
  const int lane = tid & 63;
  const int wave = tid >> 6;
  const int split = blockIdx.y;
  const int rowbase = blockIdx.x * 512 + wave * 128;   // 8 rowtiles of 16
  const int c16 = lane & 15, quad = lane >> 4;

  const _Float16* gB = Bh + (size_t)split * SPLITK * 64;  // 128 KB region

  // async-stage chunk 0 -> buf 0 (linear copy: Bh pre-swizzled in prep)
#pragma unroll
  for (int j = 0; j < 8; ++j)
    gload_lds16(gB + j * 2048 + tid * 8, &sB[0][j * 2048 + tid * 8]);

  half8 uh0[8], uh1[8];
#pragma unroll
  for (int rt = 0; rt < 8; ++rt) {
    const size_t abase = (size_t)(rowbase + rt * 16 + c16) * 64 + quad * 8;
    uh0[rt] = *(const half8*)(Ah + abase);
    uh1[rt] = *(const half8*)(Ah + abase + 32);
  }

  float a1[8][4];
#pragma unroll
  for (int rt = 0; rt < 8; ++rt)
#pragma unroll
    for (int r = 0; r < 4; ++r) a1[rt][r] = -INFINITY;

  const f32x4 fzero = {0.f, 0.f, 0.f, 0.f};
  // swizzled read offsets (halfs): row c16, physical slot = logical ^ (c16&7)
  const int key = c16 & 7;
  const int rs0h = c16 * 64 + (quad ^ key) * 8;         // p-part (slots 0-3)
  const int rs1h = c16 * 64 + ((quad + 4) ^ key) * 8;   // q-part (slots 4-7)

  __syncthreads();   // chunk 0 landed (compiler drains vmcnt before barrier)

#pragma unroll 1
  for (int ch = 0; ch < 4; ++ch) {
    if (ch < 3) {    // issue next chunk into the idle buffer (async)
      const _Float16* src = gB + (size_t)(ch + 1) * 16384;
      _Float16* dst = &sB[(ch + 1) & 1][0];
#pragma unroll
      for (int j = 0; j < 8; ++j)
        gload_lds16(src + j * 2048 + tid * 8, dst + j * 2048 + tid * 8);
    }
    const _Float16* buf = &sB[ch & 1][0];
#pragma unroll 1
    for (int tp = 0; tp < 8; ++tp) {          // 8 tile-pairs per chunk
      const _Float16* b0 = buf + (2 * tp) * 1024;
      const _Float16* b1 = b0 + 1024;
      const half8 x0 = *(const half8*)(b0 + rs0h);
      const half8 x1 = *(const half8*)(b0 + rs1h);
      const half8 y0 = *(const half8*)(b1 + rs0h);
      const half8 y1 = *(const half8*)(b1 + rs1h);
#pragma unroll
      for (int rt = 0; rt < 8; ++rt) {
        f32x4 h0 = __builtin_amdgcn_mfma_f32_16x16x32_f16(uh0[rt], x0, fzero, 0, 0, 0);
        h0 = __builtin_amdgcn_mfma_f32_16x16x32_f16(uh1[rt], x1, h0, 0, 0, 0);
        f32x4 h1 = __builtin_amdgcn_mfma_f32_16x16x32_f16(uh0[rt], y0, fzero, 0, 0, 0);
        h1 = __builtin_amdgcn_mfma_f32_16x16x32_f16(uh1[rt], y1, h1, 0, 0, 0);
#pragma unroll
        for (int r = 0; r < 4; ++r)
          a1[rt][r] = fmaxf(fmaxf(h0[r], h1[r]), a1[rt][r]);   // v_max3
      }
    }
    __syncthreads();  // all waves done with buf; next chunk landed (vmcnt 0)
  }

  // W1 fp16 [split][row][16]: block-exclusive contiguous 16KB, no RMW.
#pragma unroll
  for (int rt = 0; rt < 8; ++rt)
#pragma unroll
    for (int r = 0; r < 4; ++r) {
      const int row_r = rowbase + rt * 16 + quad * 4 + r;   // C: row=quad*4+r
      W1[((size_t)split * NROWS + row_r) * 16 + c16] =
          (_Float16)fmaxf(a1[rt][r], -65504.0f);
    }
}

// exact fp32 score, p/q broadcast from LDS (identical formula to R2)
__device__ __forceinline__ float exact_score(const float4* __restrict__ cb4,
                                             const float4* __restrict__ spq,
                                             int k) {
  float s0 = 0.0f, s1 = 0.0f, s2 = 0.0f, s3 = 0.0f;
#pragma unroll
  for (int m = 0; m < 8; ++m) {
    const float4 cv = cb4[k * 8 + m];
    const float4 pv = spq[m];        // p[4m..4m+3]
    const float4 qv = spq[8 + m];    // q[4m..4m+3]
    s0 = fmaf(cv.x, fmaf(qv.x, cv.x, pv.x), s0);
    s1 = fmaf(cv.y, fmaf(qv.y, cv.y, pv.y), s1);
    s2 = fmaf(cv.z, fmaf(qv.z, cv.z, pv.z), s2);
    s3 = fmaf(cv.w, fmaf(qv.w, cv.w, pv.w), s3);
  }
  return (s0 + s1) + (s2 + s3);
}

// 1 wave per row; 4 rows per block. Seed E* by fully rescanning the argmax
// column, then full rescan of every column with w + Btot_col >= E*. (R19)
__global__ __launch_bounds__(256, 4) void merge_kernel(const float* __restrict__ PQ,
                                                       const float* __restrict__ cb,
                                                       const _Float16* __restrict__ W1,
                                                       const float* __restrict__ CN1,
                                                       const float* __restrict__ CN2,
                                                       const double* __restrict__ klsum,
                                                       float* __restrict__ out0,
                                                       float* __restrict__ out1,
                                                       float* __restrict__ out2) {
  __shared__ float4 spq_s[4][16];
  const int lane = threadIdx.x & 63;
  const int wave = threadIdx.x >> 6;
  const int row = blockIdx.x * 4 + wave;

  if (lane < 16)
    spq_s[wave][lane] = ((const float4*)(PQ + (size_t)row * 64))[lane];
  __syncthreads();
  const float4* spq = spq_s[wave];
  const float4* __restrict__ cb4 = (const float4*)cb;

  // per-row norms ||p||2, ||q||2
  float sp = 0.0f, sq = 0.0f;
  if (lane < DIM) {
    const float pd = ((const float*)spq)[lane];
    const float qd = ((const float*)spq)[32 + lane];
    sp = pd * pd;
    sq = qd * qd;
  }
#pragma unroll
  for (int off = 1; off < 32; off <<= 1) {
    sp += __shfl_xor(sp, off);
    sq += __shfl_xor(sq, off);
  }
  const float pn = sqrtf(__shfl(sp, 0));
  const float qn = sqrtf(__shfl(sq, 0));

  // load 256 column maxima (fp16, layout [split][row][16]); col = i*64 + lane
  float w[4];
#pragma unroll
  for (int i = 0; i < 4; ++i)
    w[i] = (float)W1[((size_t)(i * 4 + (lane >> 4)) * NROWS + row) * 16 + (lane & 15)];
  float As = fmaxf(fmaxf(w[0], w[1]), fmaxf(w[2], w[3]));
#pragma unroll
  for (int off = 1; off < 64; off <<= 1) As = fmaxf(As, __shfl_xor(As, off));
  const float slack = 2e-5f * (fabsf(As) + 1.0f) + 1e-3f;

  // per-column rigorous bounds + fp16-rounding term
  float bt[4];
#pragma unroll
  for (int i = 0; i < 4; ++i) {
    const int col = i * 64 + lane;
    bt[i] = 1.05e-3f * (pn * CN1[col] + qn * CN2[col]) + slack
            + 5e-4f * fabsf(w[i]);
  }

  // ---- seed: full exact rescan of (one) column achieving As ----
  int done_col = -1;
#pragma unroll
  for (int i = 0; i < 4; ++i) {
    if (done_col < 0) {
      const unsigned long long m = __ballot(w[i] == As);
      if (m) done_col = i * 64 + __builtin_ctzll(m);
    }
  }
  const int k0 = (done_col >> 4) * SPLITK + lane * 16 + (done_col & 15);
  float best = exact_score(cb4, spq, k0);
  int bk = k0;
#pragma unroll
  for (int off = 1; off < 64; off <<= 1) {
    const float ov = __shfl_xor(best, off);
    const int ok = __shfl_xor(bk, off);
    if (ov > best || (ov == best && ok < bk)) { best = ov; bk = ok; }
  }
  const float Estar = best;   // exact score of a real k; all lanes agree

  // ---- full rescan of every other column that could still hold the max ----
#pragma unroll 1
  for (int i = 0; i < 4; ++i) {
    unsigned long long m = __ballot(w[i] + bt[i] >= Estar);
    if ((done_col >> 6) == i) m &= ~(1ull << (done_col & 63));
    while (m) {
      const int e = __builtin_ctzll(m);
      m &= m - 1;
      const int col = i * 64 + e;
      const int k = (col >> 4) * SPLITK + lane * 16 + (col & 15);
      const float sc = exact_score(cb4, spq, k);
      if (sc > best || (sc == best && k < bk)) { best = sc; bk = k; }
    }
  }
  // final cross-lane argmax, min-k on ties (numpy first-max)
#pragma unroll
  for (int off = 1; off < 64; off <<= 1) {
    const float ov = __shfl_xor(best, off);
    const int ok = __shfl_xor(bk, off);
    if (ov > best || (ov == best && ok < bk)) { best = ov; bk = ok; }
  }
  if (lane == 0) out2[row] = (float)bk;
  const int tt = row >> 3, cc = row & 7;
  if (lane < DIM) out0[tt * 256 + lane * 8 + cc] = cb[bk * DIM + lane];
  if (blockIdx.x == 0 && threadIdx.x == 0)
    out1[0] = (float)(klsum[0] * (1.4426 * 0.5) / (double)NROWS);
}

extern "C" void kernel_launch(void* const* d_in, const int* in_sizes, int n_in,
                              void* d_out, int out_size, void* d_ws, size_t ws_size,
                              hipStream_t stream) {
  const float* z  = (const float*)d_in[0];
  const float* cb = (const float*)d_in[2];   // d_in[1]=noise unused (STE cancels)

  char* ws = (char*)d_ws;
  double* klsum  = (double*)(ws + WS_KL);
  float*     CN1 = (float*)(ws + WS_CN1);
  float*     CN2 = (float*)(ws + WS_CN2);
  float*      PQ = (float*)(ws + WS_PQ);
  _Float16*   Ah = (_Float16*)(ws + WS_AH);
  _Float16*   Bh = (_Float16*)(ws + WS_BH);
  _Float16*   W1 = (_Float16*)(ws + WS_W1);

  float* out0 = (float*)d_out;            // 524288
  float* out1 = out0 + 524288;            // 1
  float* out2 = out1 + 1;                 // 16384

  (void)hipMemsetAsync(ws, 0, 4096, stream);   // klsum, CN1, CN2 = 0
  prep_kernel<<<1024, 256, 0, stream>>>(cb, z, Bh, CN1, CN2, PQ, Ah, klsum);
  dim3 fgrid(32, NSPLIT);
  filter_kernel<<<fgrid, 256, 0, stream>>>(Ah, Bh, W1);
  merge_kernel<<<NROWS / 4, 256, 0, stream>>>(PQ, cb, W1, CN1, CN2, klsum,
                                              out0, out1, out2);
}